// Round 1
// baseline (405.121 us; speedup 1.0000x reference)
//
#include <hip/hip_runtime.h>
#include <hip/hip_bf16.h>
#include <math.h>

// Problem dims (fixed by setup_inputs)
#define E_   8
#define H_   768
#define I_   3072
#define T_   2048
#define NTOK (E_ * T_)

typedef __attribute__((ext_vector_type(8))) short bf16x8;   // 8 bf16 = 4 VGPRs
typedef __attribute__((ext_vector_type(4))) float f32x4;    // MFMA accum

typedef __attribute__((address_space(3))) void lds_void;
typedef const __attribute__((address_space(1))) void gl_void;

__device__ __forceinline__ void gload16(const void* g, void* l) {
  // 16B async global->LDS. LDS dest is wave-uniform base + lane*16.
  __builtin_amdgcn_global_load_lds((gl_void*)g, (lds_void*)l, 16, 0, 0);
}

// ---------------------------------------------------------------------------
// fp32 -> bf16 elementwise convert (vectorized: float4 in, 8B out per thread)
// ---------------------------------------------------------------------------
__global__ __launch_bounds__(256) void cvt_bf16_kernel(
    const float* __restrict__ in, __hip_bfloat16* __restrict__ out) {
  int i = (blockIdx.x * 256 + threadIdx.x) * 4;
  float4 v = *(const float4*)(in + i);
  __align__(8) __hip_bfloat16 t[4];
  t[0] = __float2bfloat16(v.x);
  t[1] = __float2bfloat16(v.y);
  t[2] = __float2bfloat16(v.z);
  t[3] = __float2bfloat16(v.w);
  *(ushort4*)(out + i) = *(const ushort4*)t;
}

// ---------------------------------------------------------------------------
// [E][R][C] fp32  ->  [E][C][R] bf16  (64x64 LDS tiles, both sides coalesced)
// ---------------------------------------------------------------------------
__global__ __launch_bounds__(256) void transpose_cvt_kernel(
    const float* __restrict__ src, __hip_bfloat16* __restrict__ dst,
    int R, int C) {
  __shared__ __hip_bfloat16 tile[64][65];  // +1 pad breaks pow2 stride
  int e  = blockIdx.z;
  int c0 = blockIdx.x * 64;
  int r0 = blockIdx.y * 64;
  const float* s = src + (size_t)e * R * C;
  __hip_bfloat16* d = dst + (size_t)e * R * C;
  int tx = threadIdx.x & 63, ty = threadIdx.x >> 6;
#pragma unroll
  for (int r = ty; r < 64; r += 4)
    tile[r][tx] = __float2bfloat16(s[(size_t)(r0 + r) * C + c0 + tx]);
  __syncthreads();
#pragma unroll
  for (int r = ty; r < 64; r += 4)
    d[(size_t)(c0 + r) * R + r0 + tx] = tile[tx][r];
}

// ---------------------------------------------------------------------------
// Grouped GEMM, m97 structure: 128x128 tile, BK=64, 4 waves (2x2), each wave
// 64x64 out via 4x4 frags of mfma_f32_16x16x32_bf16. A:[E][2048][K] bf16,
// B:[E][N][K] bf16 (pre-transposed), bias:[E][N] f32, out:[E][2048][N] bf16.
// Epilogue: +bias, optional exact GELU, bf16 store.
// ---------------------------------------------------------------------------
template <int K, int N, bool GELU>
__global__ __launch_bounds__(256) void gemm_bt_kernel(
    const __hip_bfloat16* __restrict__ A,
    const __hip_bfloat16* __restrict__ B,
    const float* __restrict__ bias,
    __hip_bfloat16* __restrict__ out) {
  constexpr int MT = T_ / 128;
  constexpr int NT = N / 128;
  constexpr int KT = K / 64;

  __shared__ __hip_bfloat16 sA[128 * 64];
  __shared__ __hip_bfloat16 sB[128 * 64];

  int bid = blockIdx.x;
  int e   = bid / (MT * NT);
  int rr_ = bid % (MT * NT);
  int bm  = rr_ / NT;
  int bn  = rr_ % NT;

  const __hip_bfloat16* Ae = A + (size_t)e * T_ * K + (size_t)bm * 128 * K;
  const __hip_bfloat16* Be = B + (size_t)e * N * K + (size_t)bn * 128 * K;

  int tid  = threadIdx.x;
  int lane = tid & 63;
  int wid  = tid >> 6;
  int wm   = wid >> 1, wn = wid & 1;  // 2x2 wave grid
  int l15  = lane & 15;
  int lk   = (lane >> 4) * 8;         // k-offset within a 32-slice

  f32x4 acc[4][4] = {};

  for (int kt = 0; kt < KT; ++kt) {
    __syncthreads();  // previous compute done before overwrite
    const __hip_bfloat16* gA = Ae + kt * 64;
    const __hip_bfloat16* gB = Be + kt * 64;
#pragma unroll
    for (int t = 0; t < 4; ++t) {
      int cbase = t * 256 + (wid << 6);   // wave-uniform chunk base
      int c     = cbase + lane;
      int row   = c >> 3;
      int k8    = (c & 7) * 8;
      gload16(gA + (size_t)row * K + k8, sA + (size_t)cbase * 8);
      gload16(gB + (size_t)row * K + k8, sB + (size_t)cbase * 8);
    }
    __syncthreads();  // compiler drains vmcnt before barrier
#pragma unroll
    for (int ks = 0; ks < 2; ++ks) {
      bf16x8 af[4], bfv[4];
#pragma unroll
      for (int m = 0; m < 4; ++m)
        af[m] = *(const bf16x8*)&sA[(wm * 64 + m * 16 + l15) * 64 + ks * 32 + lk];
#pragma unroll
      for (int n = 0; n < 4; ++n)
        bfv[n] = *(const bf16x8*)&sB[(wn * 64 + n * 16 + l15) * 64 + ks * 32 + lk];
#pragma unroll
      for (int m = 0; m < 4; ++m)
#pragma unroll
        for (int n = 0; n < 4; ++n)
          acc[m][n] = __builtin_amdgcn_mfma_f32_16x16x32_bf16(
              af[m], bfv[n], acc[m][n], 0, 0, 0);
    }
  }

  // Epilogue. C/D mapping (m89-verified): col = lane&15, row = (lane>>4)*4 + r.
  const float* be = bias + (size_t)e * N + bn * 128;
  __hip_bfloat16* oe =
      out + (size_t)e * T_ * N + (size_t)(bm * 128) * N + bn * 128;
  int r4 = (lane >> 4) * 4;
#pragma unroll
  for (int m = 0; m < 4; ++m) {
#pragma unroll
    for (int n = 0; n < 4; ++n) {
      int cc   = wn * 64 + n * 16 + l15;
      float bv = be[cc];
#pragma unroll
      for (int r = 0; r < 4; ++r) {
        int row = wm * 64 + m * 16 + r4 + r;
        float v = acc[m][n][r] + bv;
        if (GELU) v = 0.5f * v * (1.0f + erff(v * 0.70710678118654752f));
        oe[(size_t)row * N + cc] = __float2bfloat16(v);
      }
    }
  }
}

// ---------------------------------------------------------------------------
// Residual + LayerNorm: one 256-thread block per token row (H=768 = 3*256).
// y = yraw(bf16) + x(f32); out = (y-mean)*rsqrt(var+eps)*gamma + beta (f32).
// ---------------------------------------------------------------------------
__global__ __launch_bounds__(256) void ln_kernel(
    const __hip_bfloat16* __restrict__ yraw, const float* __restrict__ x,
    const float* __restrict__ gamma, const float* __restrict__ beta,
    float* __restrict__ out) {
  int row  = blockIdx.x;
  int tid  = threadIdx.x;
  int lane = tid & 63, wid = tid >> 6;
  const __hip_bfloat16* yr = yraw + (size_t)row * H_;
  const float* xr = x + (size_t)row * H_;

  float v[3];
  float s = 0.f, s2 = 0.f;
#pragma unroll
  for (int j = 0; j < 3; ++j) {
    int c   = tid + j * 256;
    float t = __bfloat162float(yr[c]) + xr[c];
    v[j] = t;
    s += t;
    s2 += t * t;
  }
#pragma unroll
  for (int o = 32; o > 0; o >>= 1) {
    s  += __shfl_down(s, o);
    s2 += __shfl_down(s2, o);
  }
  __shared__ float ls[4], ls2[4];
  if (lane == 0) { ls[wid] = s; ls2[wid] = s2; }
  __syncthreads();
  float tot  = ls[0] + ls[1] + ls[2] + ls[3];
  float tot2 = ls2[0] + ls2[1] + ls2[2] + ls2[3];
  float mean = tot * (1.0f / 768.0f);
  float var  = tot2 * (1.0f / 768.0f) - mean * mean;
  float inv  = rsqrtf(var + 1e-12f);
  float* orow = out + (size_t)row * H_;
#pragma unroll
  for (int j = 0; j < 3; ++j) {
    int c = tid + j * 256;
    orow[c] = (v[j] - mean) * inv * gamma[c] + beta[c];
  }
}

// ---------------------------------------------------------------------------
extern "C" void kernel_launch(void* const* d_in, const int* in_sizes, int n_in,
                              void* d_out, int out_size, void* d_ws,
                              size_t ws_size, hipStream_t stream) {
  const float* x     = (const float*)d_in[0];  // [N, H]
  const float* w1    = (const float*)d_in[1];  // [E, H, I]
  const float* b1    = (const float*)d_in[2];  // [E, I]
  const float* w2    = (const float*)d_in[3];  // [E, I, H]
  const float* b2    = (const float*)d_in[4];  // [E, H]
  const float* gamma = (const float*)d_in[5];  // [H]
  const float* beta  = (const float*)d_in[6];  // [H]
  float* out = (float*)d_out;

  // Workspace layout (192 MiB total):
  //   w1t  [E][I][H] bf16 : 37,748,736 B @ 0
  //   w2t  [E][H][I] bf16 : 37,748,736 B @ 37748736
  //   x_bf [N][H]    bf16 : 25,165,824 B @ 75497472   (aliased by yraw later)
  //   inter[E][T][I] bf16 :100,663,296 B @ 100663296
  char* ws = (char*)d_ws;
  __hip_bfloat16* w1t   = (__hip_bfloat16*)(ws);
  __hip_bfloat16* w2t   = (__hip_bfloat16*)(ws + 37748736);
  __hip_bfloat16* x_bf  = (__hip_bfloat16*)(ws + 75497472);
  __hip_bfloat16* inter = (__hip_bfloat16*)(ws + 100663296);
  __hip_bfloat16* yraw  = x_bf;  // x_bf dead after GEMM1; safe alias

  // 1) convert residual input to bf16 (12.58M elems / 4 per thread)
  cvt_bf16_kernel<<<(NTOK * H_) / (256 * 4), 256, 0, stream>>>(x, x_bf);
  // 2) w1 [E][H][I] -> w1t [E][I][H] bf16
  transpose_cvt_kernel<<<dim3(I_ / 64, H_ / 64, E_), 256, 0, stream>>>(
      w1, w1t, H_, I_);
  // 3) w2 [E][I][H] -> w2t [E][H][I] bf16
  transpose_cvt_kernel<<<dim3(H_ / 64, I_ / 64, E_), 256, 0, stream>>>(
      w2, w2t, I_, H_);
  // 4) GEMM1 + bias + exact GELU -> inter
  gemm_bt_kernel<H_, I_, true>
      <<<E_ * (T_ / 128) * (I_ / 128), 256, 0, stream>>>(x_bf, w1t, b1, inter);
  // 5) GEMM2 + bias -> yraw
  gemm_bt_kernel<I_, H_, false>
      <<<E_ * (T_ / 128) * (H_ / 128), 256, 0, stream>>>(inter, w2t, b2, yraw);
  // 6) residual + LayerNorm -> out (fp32)
  ln_kernel<<<NTOK, 256, 0, stream>>>(yraw, x, gamma, beta, out);
}

// Round 2
// 404.874 us; speedup vs baseline: 1.0006x; 1.0006x over previous
//
#include <hip/hip_runtime.h>
#include <hip/hip_bf16.h>
#include <math.h>

// Problem dims (fixed by setup_inputs)
#define E_   8
#define H_   768
#define I_   3072
#define T_   2048
#define NTOK (E_ * T_)

typedef __attribute__((ext_vector_type(8))) short bf16x8;   // 8 bf16 = 4 VGPRs
typedef __attribute__((ext_vector_type(4))) float f32x4;    // MFMA accum

typedef __attribute__((address_space(3))) void lds_void;
typedef const __attribute__((address_space(1))) void gl_void;

__device__ __forceinline__ void gload16(const void* g, void* l) {
  // 16B async global->LDS. LDS dest is wave-uniform base + lane*16.
  __builtin_amdgcn_global_load_lds((gl_void*)g, (lds_void*)l, 16, 0, 0);
}

// Fast exact-enough GELU: v * sigmoid(1.5957691*(v + 0.044715 v^3)).
// sigmoid via exp2: 1/(1+2^(-1.4427*y)). |err| vs erf-GELU ~3e-4 << bf16
// storage error (~0.02) of the intermediate. Saturates cleanly at +-inf.
__device__ __forceinline__ float gelu_fast(float v) {
  float inner = v * fmaf(v * v, 0.044715f, 1.0f);
  float e = __builtin_amdgcn_exp2f(inner * -2.3022082f);  // 1.59577*1.44270
  return v * __builtin_amdgcn_rcpf(1.0f + e);
}

// ---------------------------------------------------------------------------
// fp32 -> bf16 elementwise convert (vectorized: float4 in, 8B out per thread)
// ---------------------------------------------------------------------------
__global__ __launch_bounds__(256) void cvt_bf16_kernel(
    const float* __restrict__ in, __hip_bfloat16* __restrict__ out) {
  int i = (blockIdx.x * 256 + threadIdx.x) * 4;
  float4 v = *(const float4*)(in + i);
  __align__(8) __hip_bfloat16 t[4];
  t[0] = __float2bfloat16(v.x);
  t[1] = __float2bfloat16(v.y);
  t[2] = __float2bfloat16(v.z);
  t[3] = __float2bfloat16(v.w);
  *(ushort4*)(out + i) = *(const ushort4*)t;
}

// ---------------------------------------------------------------------------
// [E][R][C] fp32  ->  [E][C][R] bf16  (64x64 LDS tiles, both sides coalesced)
// ---------------------------------------------------------------------------
__global__ __launch_bounds__(256) void transpose_cvt_kernel(
    const float* __restrict__ src, __hip_bfloat16* __restrict__ dst,
    int R, int C) {
  __shared__ __hip_bfloat16 tile[64][65];  // +1 pad breaks pow2 stride
  int e  = blockIdx.z;
  int c0 = blockIdx.x * 64;
  int r0 = blockIdx.y * 64;
  const float* s = src + (size_t)e * R * C;
  __hip_bfloat16* d = dst + (size_t)e * R * C;
  int tx = threadIdx.x & 63, ty = threadIdx.x >> 6;
#pragma unroll
  for (int r = ty; r < 64; r += 4)
    tile[r][tx] = __float2bfloat16(s[(size_t)(r0 + r) * C + c0 + tx]);
  __syncthreads();
#pragma unroll
  for (int r = ty; r < 64; r += 4)
    d[(size_t)(c0 + r) * R + r0 + tx] = tile[tx][r];
}

// ---------------------------------------------------------------------------
// Grouped GEMM, T3-minimum structure: 128x128 tile, BK=64, 4 waves (2x2),
// double-buffered LDS, ONE barrier per K-step: STAGE(next) is issued before
// ds_read+MFMA(cur); __syncthreads() (drains vmcnt+lgkmcnt) ends the step.
// Load of tile t+1 overlaps compute of tile t.
// A:[E][2048][K] bf16, B:[E][N][K] bf16 (pre-transposed), bias:[E][N] f32,
// out:[E][2048][N] bf16. Epilogue: +bias, optional fast-GELU, bf16 store.
// ---------------------------------------------------------------------------
template <int K, int N, bool GELU>
__global__ __launch_bounds__(256) void gemm_bt_kernel(
    const __hip_bfloat16* __restrict__ A,
    const __hip_bfloat16* __restrict__ B,
    const float* __restrict__ bias,
    __hip_bfloat16* __restrict__ out) {
  constexpr int MT = T_ / 128;
  constexpr int NT = N / 128;
  constexpr int KT = K / 64;

  __shared__ __hip_bfloat16 sA[2][128 * 64];
  __shared__ __hip_bfloat16 sB[2][128 * 64];

  // T1: bijective XCD swizzle (gridDim.x % 8 == 0 for both GEMMs here).
  int nwg  = gridDim.x;
  int bid0 = blockIdx.x;
  int bid  = (bid0 & 7) * (nwg >> 3) + (bid0 >> 3);

  int e   = bid / (MT * NT);
  int rr_ = bid % (MT * NT);
  int bm  = rr_ / NT;  // bn-minor: consecutive logical ids share the A panel
  int bn  = rr_ % NT;

  const __hip_bfloat16* Ae = A + (size_t)e * T_ * K + (size_t)bm * 128 * K;
  const __hip_bfloat16* Be = B + (size_t)e * N * K + (size_t)bn * 128 * K;

  int tid  = threadIdx.x;
  int lane = tid & 63;
  int wid  = tid >> 6;
  int wm   = wid >> 1, wn = wid & 1;  // 2x2 wave grid
  int l15  = lane & 15;
  int lk   = (lane >> 4) * 8;         // k-offset within a 32-slice

  f32x4 acc[4][4] = {};

  auto stage = [&](int buf, int kt) {
    const __hip_bfloat16* gA = Ae + kt * 64;
    const __hip_bfloat16* gB = Be + kt * 64;
#pragma unroll
    for (int t = 0; t < 4; ++t) {
      int cbase = t * 256 + (wid << 6);  // wave-uniform chunk base
      int c     = cbase + lane;
      int row   = c >> 3;
      int k8    = (c & 7) * 8;
      gload16(gA + (size_t)row * K + k8, &sA[buf][cbase * 8]);
      gload16(gB + (size_t)row * K + k8, &sB[buf][cbase * 8]);
    }
  };

  stage(0, 0);
  __syncthreads();  // drains vmcnt(0): buf0 ready

  int cur = 0;
  for (int kt = 0; kt < KT; ++kt) {
    if (kt + 1 < KT) stage(cur ^ 1, kt + 1);  // prefetch overlaps compute
#pragma unroll
    for (int ks = 0; ks < 2; ++ks) {
      bf16x8 af[4], bfv[4];
#pragma unroll
      for (int m = 0; m < 4; ++m)
        af[m] =
            *(const bf16x8*)&sA[cur][(wm * 64 + m * 16 + l15) * 64 + ks * 32 + lk];
#pragma unroll
      for (int n = 0; n < 4; ++n)
        bfv[n] =
            *(const bf16x8*)&sB[cur][(wn * 64 + n * 16 + l15) * 64 + ks * 32 + lk];
#pragma unroll
      for (int m = 0; m < 4; ++m)
#pragma unroll
        for (int n = 0; n < 4; ++n)
          acc[m][n] = __builtin_amdgcn_mfma_f32_16x16x32_bf16(
              af[m], bfv[n], acc[m][n], 0, 0, 0);
    }
    __syncthreads();  // drains stage loads (vmcnt) + ds_reads (lgkm); one barrier/step
    cur ^= 1;
  }

  // Epilogue. C/D mapping (m89-verified): col = lane&15, row = (lane>>4)*4 + r.
  const float* be = bias + (size_t)e * N + bn * 128;
  __hip_bfloat16* oe =
      out + (size_t)e * T_ * N + (size_t)(bm * 128) * N + bn * 128;
  int r4 = (lane >> 4) * 4;
#pragma unroll
  for (int m = 0; m < 4; ++m) {
#pragma unroll
    for (int n = 0; n < 4; ++n) {
      int cc   = wn * 64 + n * 16 + l15;
      float bv = be[cc];
#pragma unroll
      for (int r = 0; r < 4; ++r) {
        int row = wm * 64 + m * 16 + r4 + r;
        float v = acc[m][n][r] + bv;
        if (GELU) v = gelu_fast(v);
        oe[(size_t)row * N + cc] = __float2bfloat16(v);
      }
    }
  }
}

// ---------------------------------------------------------------------------
// Residual + LayerNorm: one 256-thread block per token row (H=768 = 3*256).
// y = yraw(bf16) + x(f32); out = (y-mean)*rsqrt(var+eps)*gamma + beta (f32).
// ---------------------------------------------------------------------------
__global__ __launch_bounds__(256) void ln_kernel(
    const __hip_bfloat16* __restrict__ yraw, const float* __restrict__ x,
    const float* __restrict__ gamma, const float* __restrict__ beta,
    float* __restrict__ out) {
  int row  = blockIdx.x;
  int tid  = threadIdx.x;
  int lane = tid & 63, wid = tid >> 6;
  const __hip_bfloat16* yr = yraw + (size_t)row * H_;
  const float* xr = x + (size_t)row * H_;

  float v[3];
  float s = 0.f, s2 = 0.f;
#pragma unroll
  for (int j = 0; j < 3; ++j) {
    int c   = tid + j * 256;
    float t = __bfloat162float(yr[c]) + xr[c];
    v[j] = t;
    s += t;
    s2 += t * t;
  }
#pragma unroll
  for (int o = 32; o > 0; o >>= 1) {
    s  += __shfl_down(s, o);
    s2 += __shfl_down(s2, o);
  }
  __shared__ float ls[4], ls2[4];
  if (lane == 0) { ls[wid] = s; ls2[wid] = s2; }
  __syncthreads();
  float tot  = ls[0] + ls[1] + ls[2] + ls[3];
  float tot2 = ls2[0] + ls2[1] + ls2[2] + ls2[3];
  float mean = tot * (1.0f / 768.0f);
  float var  = tot2 * (1.0f / 768.0f) - mean * mean;
  float inv  = rsqrtf(var + 1e-12f);
  float* orow = out + (size_t)row * H_;
#pragma unroll
  for (int j = 0; j < 3; ++j) {
    int c = tid + j * 256;
    orow[c] = (v[j] - mean) * inv * gamma[c] + beta[c];
  }
}

// ---------------------------------------------------------------------------
extern "C" void kernel_launch(void* const* d_in, const int* in_sizes, int n_in,
                              void* d_out, int out_size, void* d_ws,
                              size_t ws_size, hipStream_t stream) {
  const float* x     = (const float*)d_in[0];  // [N, H]
  const float* w1    = (const float*)d_in[1];  // [E, H, I]
  const float* b1    = (const float*)d_in[2];  // [E, I]
  const float* w2    = (const float*)d_in[3];  // [E, I, H]
  const float* b2    = (const float*)d_in[4];  // [E, H]
  const float* gamma = (const float*)d_in[5];  // [H]
  const float* beta  = (const float*)d_in[6];  // [H]
  float* out = (float*)d_out;

  // Workspace layout (192 MiB total):
  //   w1t  [E][I][H] bf16 : 37,748,736 B @ 0
  //   w2t  [E][H][I] bf16 : 37,748,736 B @ 37748736
  //   x_bf [N][H]    bf16 : 25,165,824 B @ 75497472   (aliased by yraw later)
  //   inter[E][T][I] bf16 :100,663,296 B @ 100663296
  char* ws = (char*)d_ws;
  __hip_bfloat16* w1t   = (__hip_bfloat16*)(ws);
  __hip_bfloat16* w2t   = (__hip_bfloat16*)(ws + 37748736);
  __hip_bfloat16* x_bf  = (__hip_bfloat16*)(ws + 75497472);
  __hip_bfloat16* inter = (__hip_bfloat16*)(ws + 100663296);
  __hip_bfloat16* yraw  = x_bf;  // x_bf dead after GEMM1; safe alias

  // 1) convert residual input to bf16 (12.58M elems / 4 per thread)
  cvt_bf16_kernel<<<(NTOK * H_) / (256 * 4), 256, 0, stream>>>(x, x_bf);
  // 2) w1 [E][H][I] -> w1t [E][I][H] bf16
  transpose_cvt_kernel<<<dim3(I_ / 64, H_ / 64, E_), 256, 0, stream>>>(
      w1, w1t, H_, I_);
  // 3) w2 [E][I][H] -> w2t [E][H][I] bf16
  transpose_cvt_kernel<<<dim3(H_ / 64, I_ / 64, E_), 256, 0, stream>>>(
      w2, w2t, I_, H_);
  // 4) GEMM1 + bias + fast GELU -> inter
  gemm_bt_kernel<H_, I_, true>
      <<<E_ * (T_ / 128) * (I_ / 128), 256, 0, stream>>>(x_bf, w1t, b1, inter);
  // 5) GEMM2 + bias -> yraw
  gemm_bt_kernel<I_, H_, false>
      <<<E_ * (T_ / 128) * (H_ / 128), 256, 0, stream>>>(inter, w2t, b2, yraw);
  // 6) residual + LayerNorm -> out (fp32)
  ln_kernel<<<NTOK, 256, 0, stream>>>(yraw, x, gamma, beta, out);
}

// Round 3
// 267.765 us; speedup vs baseline: 1.5130x; 1.5121x over previous
//
#include <hip/hip_runtime.h>
#include <hip/hip_bf16.h>
#include <math.h>

// Problem dims (fixed by setup_inputs)
#define E_   8
#define H_   768
#define I_   3072
#define T_   2048
#define NTOK (E_ * T_)

typedef __attribute__((ext_vector_type(8))) short bf16x8;   // 8 bf16 = 4 VGPRs
typedef __attribute__((ext_vector_type(4))) float f32x4;    // MFMA accum

typedef __attribute__((address_space(3))) void lds_void;
typedef const __attribute__((address_space(1))) void gl_void;

__device__ __forceinline__ void gload16(const void* g, void* l) {
  // 16B async global->LDS. LDS dest is wave-uniform base + lane*16.
  __builtin_amdgcn_global_load_lds((gl_void*)g, (lds_void*)l, 16, 0, 0);
}

// Compiler-only fence (0 instructions) + raw HW barrier. NOT __syncthreads():
// that would emit s_waitcnt vmcnt(0) and drain the prefetch pipeline (T4).
#define FENCE() asm volatile("" ::: "memory")
#define BAR()                         \
  do {                                \
    FENCE();                          \
    __builtin_amdgcn_s_barrier();     \
    FENCE();                          \
  } while (0)
#define VMWAIT(n) asm volatile("s_waitcnt vmcnt(" #n ")" ::: "memory")

#define MFMA16(a, b, c) __builtin_amdgcn_mfma_f32_16x16x32_bf16(a, b, c, 0, 0, 0)

// Fast GELU: v * sigmoid(1.5957691*(v + 0.044715 v^3)); |err| ~3e-4 << bf16
// storage error of the intermediate. (Round-2 verified, absmax 0.031.)
__device__ __forceinline__ float gelu_fast(float v) {
  float inner = v * fmaf(v * v, 0.044715f, 1.0f);
  float e = __builtin_amdgcn_exp2f(inner * -2.3022082f);
  return v * __builtin_amdgcn_rcpf(1.0f + e);
}

// ---------------------------------------------------------------------------
// fp32 -> bf16 elementwise convert
// ---------------------------------------------------------------------------
__global__ __launch_bounds__(256) void cvt_bf16_kernel(
    const float* __restrict__ in, __hip_bfloat16* __restrict__ out) {
  int i = (blockIdx.x * 256 + threadIdx.x) * 4;
  float4 v = *(const float4*)(in + i);
  __align__(8) __hip_bfloat16 t[4];
  t[0] = __float2bfloat16(v.x);
  t[1] = __float2bfloat16(v.y);
  t[2] = __float2bfloat16(v.z);
  t[3] = __float2bfloat16(v.w);
  *(ushort4*)(out + i) = *(const ushort4*)t;
}

// ---------------------------------------------------------------------------
// [E][R][C] fp32 -> [E][C][R] bf16 (64x64 LDS tiles)
// ---------------------------------------------------------------------------
__global__ __launch_bounds__(256) void transpose_cvt_kernel(
    const float* __restrict__ src, __hip_bfloat16* __restrict__ dst,
    int R, int C) {
  __shared__ __hip_bfloat16 tile[64][65];
  int e  = blockIdx.z;
  int c0 = blockIdx.x * 64;
  int r0 = blockIdx.y * 64;
  const float* s = src + (size_t)e * R * C;
  __hip_bfloat16* d = dst + (size_t)e * R * C;
  int tx = threadIdx.x & 63, ty = threadIdx.x >> 6;
#pragma unroll
  for (int r = ty; r < 64; r += 4)
    tile[r][tx] = __float2bfloat16(s[(size_t)(r0 + r) * C + c0 + tx]);
  __syncthreads();
#pragma unroll
  for (int r = ty; r < 64; r += 4)
    d[(size_t)(c0 + r) * R + r0 + tx] = tile[tx][r];
}

// ---------------------------------------------------------------------------
// Grouped GEMM, 256x256 8-phase template (T1+T2+T3+T4+T5), BK=64, 512 thr
// = 8 waves (2M x 4N), per-wave 128x64 out, mfma_f32_16x16x32_bf16.
//
// LDS: sA/sB[2 buf][2 half][128][64] bf16 = 128 KiB total.
//   A-half h = tile rows {r : (r>>6)&1 == h}  (64-row granules interleaved)
//   B-half h = tile cols {n : (n>>5)&1 == h}  (32-col granules interleaved)
// so phase quadrants (mh,nh) in order (0,0)(0,1)(1,1)(1,0) each first-need
// exactly one new half: A0@P0,B0@P0,B1@P1,A1@P2.
//
// Stage order per K-tile kt (targets buf p^1, data kt+1): P0:A0' P1:B0'
// P2:B1' P3:A1'. Counted waits (FIFO vmcnt, 2 loads/half-tile):
//   end-P1: vmcnt(4)  -> lands A1(kt)   [needed at P2]
//   end-P3: vmcnt(2)  -> lands A0',B0',B1'(kt+1) [needed at P0',P1']
// Steady-state invariant entering kt-P0: outstanding = {A1(kt)}.
// Never vmcnt(0) in-loop; last K-tile peeled with vmcnt(0) at end-P1.
//
// T2 swizzle: LDS write linear (gload_lds), global source col-group
// pre-swizzled cg = c8 ^ (lr&7); reads XOR the same: 16-way -> 2-way free.
// ---------------------------------------------------------------------------
template <int K, int N, bool GELU>
__global__ __launch_bounds__(512, 2) void gemm8p_kernel(
    const __hip_bfloat16* __restrict__ A,
    const __hip_bfloat16* __restrict__ B,
    const float* __restrict__ bias,
    __hip_bfloat16* __restrict__ out) {
  constexpr int MT = T_ / 256;
  constexpr int NT = N / 256;
  constexpr int KT = K / 64;

  __shared__ __hip_bfloat16 sA[2][2][128][64];
  __shared__ __hip_bfloat16 sB[2][2][128][64];

  // T1: bijective XCD swizzle (gridDim.x % 8 == 0 for both GEMMs).
  int nwg = gridDim.x;
  int b0  = blockIdx.x;
  int bid = (b0 & 7) * (nwg >> 3) + (b0 >> 3);

  int e   = bid / (MT * NT);
  int rr_ = bid % (MT * NT);
  int bm  = rr_ / NT;
  int bn  = rr_ % NT;

  const __hip_bfloat16* Ae = A + (size_t)e * T_ * K + (size_t)bm * 256 * K;
  const __hip_bfloat16* Be = B + (size_t)e * N  * K + (size_t)bn * 256 * K;

  int tid  = threadIdx.x;
  int lane = tid & 63;
  int wid  = tid >> 6;
  int wr   = wid >> 2;   // 0..1 (M)
  int wc   = wid & 3;    // 0..3 (N)
  int l15  = lane & 15;
  int l16h = lane >> 4;  // 0..3

  // --- staging geometry: idx = l*512 + tid, lr = idx>>3, c8 = idx&7
  int i0 = tid, i1 = 512 + tid;
  int lr0 = i0 >> 3, c80 = i0 & 7, cg0 = c80 ^ (lr0 & 7);
  int lr1 = i1 >> 3, c81 = i1 & 7, cg1 = c81 ^ (lr1 & 7);
  int rA0 = ((lr0 >> 6) << 7) | (lr0 & 63);  // + h<<6
  int rA1 = ((lr1 >> 6) << 7) | (lr1 & 63);
  int rB0 = ((lr0 >> 5) << 6) | (lr0 & 31);  // + h<<5
  int rB1 = ((lr1 >> 5) << 6) | (lr1 & 31);

  auto stageA = [&](int buf, int h, int kt) {
    const __hip_bfloat16* g = Ae + (size_t)kt * 64;
    gload16(g + (size_t)(rA0 | (h << 6)) * K + cg0 * 8, &sA[buf][h][lr0][c80 * 8]);
    gload16(g + (size_t)(rA1 | (h << 6)) * K + cg1 * 8, &sA[buf][h][lr1][c81 * 8]);
  };
  auto stageB = [&](int buf, int h, int kt) {
    const __hip_bfloat16* g = Be + (size_t)kt * 64;
    gload16(g + (size_t)(rB0 | (h << 5)) * K + cg0 * 8, &sB[buf][h][lr0][c80 * 8]);
    gload16(g + (size_t)(rB1 | (h << 5)) * K + cg1 * 8, &sB[buf][h][lr1][c81 * 8]);
  };

  // --- fragment-read geometry (T2 read-side XOR; la&7 == lbB&7 == l15&7)
  int laBase = wr * 64 + l15;  // + mf*16, within A-half
  int lbBase = wc * 32 + l15;  // + (nf&1)*16, within B-half
  int s7   = l15 & 7;
  int cgr0 = ((0 | l16h) ^ s7) * 8;  // ks=0 element offset
  int cgr1 = ((4 | l16h) ^ s7) * 8;  // ks=1

  f32x4 acc[8][4] = {};  // [mh*4+mf][nf]
  bf16x8 af[4][2], bfv[4][2];

  // ---- prologue: K-tile 0, issue order A0 B0 B1 A1 (A1 last = invariant)
  stageA(0, 0, 0);
  stageB(0, 0, 0);
  stageB(0, 1, 0);
  stageA(0, 1, 0);
  VMWAIT(2);  // lands A0,B0,B1(0); leaves {A1(0)} in flight
  BAR();

  auto ktile = [&](int kt, int p, bool pf) {
    // ---- P0: quadrant (mh0, nh0) --- 12 ds_reads, stage A-half0(kt+1)
#pragma unroll
    for (int mf = 0; mf < 4; ++mf) {
      int la = laBase + mf * 16;
      af[mf][0] = *(const bf16x8*)&sA[p][0][la][cgr0];
      af[mf][1] = *(const bf16x8*)&sA[p][0][la][cgr1];
    }
#pragma unroll
    for (int nf = 0; nf < 2; ++nf) {
      int lb = lbBase + nf * 16;
      bfv[nf][0] = *(const bf16x8*)&sB[p][0][lb][cgr0];
      bfv[nf][1] = *(const bf16x8*)&sB[p][0][lb][cgr1];
    }
    if (pf) stageA(p ^ 1, 0, kt + 1);
    BAR();
    __builtin_amdgcn_s_setprio(1);
#pragma unroll
    for (int mf = 0; mf < 4; ++mf)
#pragma unroll
      for (int nf = 0; nf < 2; ++nf) {
        acc[mf][nf] = MFMA16(af[mf][0], bfv[nf][0], acc[mf][nf]);
        acc[mf][nf] = MFMA16(af[mf][1], bfv[nf][1], acc[mf][nf]);
      }
    __builtin_amdgcn_s_setprio(0);
    BAR();
    // ---- P1: (mh0, nh1) --- 4 ds_reads, stage B-half0(kt+1)
#pragma unroll
    for (int nf = 0; nf < 2; ++nf) {
      int lb = lbBase + nf * 16;
      bfv[2 + nf][0] = *(const bf16x8*)&sB[p][1][lb][cgr0];
      bfv[2 + nf][1] = *(const bf16x8*)&sB[p][1][lb][cgr1];
    }
    if (pf) stageB(p ^ 1, 0, kt + 1);
    BAR();
    __builtin_amdgcn_s_setprio(1);
#pragma unroll
    for (int mf = 0; mf < 4; ++mf)
#pragma unroll
      for (int nf = 2; nf < 4; ++nf) {
        acc[mf][nf] = MFMA16(af[mf][0], bfv[nf][0], acc[mf][nf]);
        acc[mf][nf] = MFMA16(af[mf][1], bfv[nf][1], acc[mf][nf]);
      }
    __builtin_amdgcn_s_setprio(0);
    if (pf) { VMWAIT(4); } else { VMWAIT(0); }  // lands A1(kt) before P2 reads
    BAR();
    // ---- P2: (mh1, nh1) --- 8 ds_reads (af overwrite), stage B-half1(kt+1)
#pragma unroll
    for (int mf = 0; mf < 4; ++mf) {
      int la = laBase + mf * 16;
      af[mf][0] = *(const bf16x8*)&sA[p][1][la][cgr0];
      af[mf][1] = *(const bf16x8*)&sA[p][1][la][cgr1];
    }
    if (pf) stageB(p ^ 1, 1, kt + 1);
    BAR();
    __builtin_amdgcn_s_setprio(1);
#pragma unroll
    for (int mf = 0; mf < 4; ++mf)
#pragma unroll
      for (int nf = 2; nf < 4; ++nf) {
        acc[4 + mf][nf] = MFMA16(af[mf][0], bfv[nf][0], acc[4 + mf][nf]);
        acc[4 + mf][nf] = MFMA16(af[mf][1], bfv[nf][1], acc[4 + mf][nf]);
      }
    __builtin_amdgcn_s_setprio(0);
    BAR();
    // ---- P3: (mh1, nh0) --- 0 ds_reads, stage A-half1(kt+1)
    if (pf) stageA(p ^ 1, 1, kt + 1);
    BAR();
    __builtin_amdgcn_s_setprio(1);
#pragma unroll
    for (int mf = 0; mf < 4; ++mf)
#pragma unroll
      for (int nf = 0; nf < 2; ++nf) {
        acc[4 + mf][nf] = MFMA16(af[mf][0], bfv[nf][0], acc[4 + mf][nf]);
        acc[4 + mf][nf] = MFMA16(af[mf][1], bfv[nf][1], acc[4 + mf][nf]);
      }
    __builtin_amdgcn_s_setprio(0);
    if (pf) VMWAIT(2);  // lands A0',B0',B1'(kt+1); leaves {A1'(kt+1)}
    BAR();
  };

  int p = 0;
  for (int kt = 0; kt < KT - 1; ++kt) {
    ktile(kt, p, true);
    p ^= 1;
  }
  ktile(KT - 1, p, false);  // peeled: no prefetch, vmcnt(0) at end-P1

  // ---- epilogue: +bias, optional GELU, bf16 store.
  // C/D mapping (m89): col = lane&15, row = (lane>>4)*4 + r.
  const float* be = bias + (size_t)e * N + bn * 256;
  __hip_bfloat16* oe =
      out + (size_t)e * T_ * N + (size_t)(bm * 256) * N + bn * 256;
  int r4 = l16h * 4;
#pragma unroll
  for (int mi = 0; mi < 8; ++mi) {
    int mh = mi >> 2, mf = mi & 3;
    int rowb = wr * 128 + mh * 64 + mf * 16 + r4;
#pragma unroll
    for (int nf = 0; nf < 4; ++nf) {
      int cc   = wc * 64 + nf * 16 + l15;
      float bv = be[cc];
#pragma unroll
      for (int r = 0; r < 4; ++r) {
        float v = acc[mi][nf][r] + bv;
        if (GELU) v = gelu_fast(v);
        oe[(size_t)(rowb + r) * N + cc] = __float2bfloat16(v);
      }
    }
  }
}

// ---------------------------------------------------------------------------
// Residual + LayerNorm: one 256-thread block per token row (H=768 = 3*256).
// ---------------------------------------------------------------------------
__global__ __launch_bounds__(256) void ln_kernel(
    const __hip_bfloat16* __restrict__ yraw, const float* __restrict__ x,
    const float* __restrict__ gamma, const float* __restrict__ beta,
    float* __restrict__ out) {
  int row  = blockIdx.x;
  int tid  = threadIdx.x;
  int lane = tid & 63, wid = tid >> 6;
  const __hip_bfloat16* yr = yraw + (size_t)row * H_;
  const float* xr = x + (size_t)row * H_;

  float v[3];
  float s = 0.f, s2 = 0.f;
#pragma unroll
  for (int j = 0; j < 3; ++j) {
    int c   = tid + j * 256;
    float t = __bfloat162float(yr[c]) + xr[c];
    v[j] = t;
    s += t;
    s2 += t * t;
  }
#pragma unroll
  for (int o = 32; o > 0; o >>= 1) {
    s  += __shfl_down(s, o);
    s2 += __shfl_down(s2, o);
  }
  __shared__ float ls[4], ls2[4];
  if (lane == 0) { ls[wid] = s; ls2[wid] = s2; }
  __syncthreads();
  float tot  = ls[0] + ls[1] + ls[2] + ls[3];
  float tot2 = ls2[0] + ls2[1] + ls2[2] + ls2[3];
  float mean = tot * (1.0f / 768.0f);
  float var  = tot2 * (1.0f / 768.0f) - mean * mean;
  float inv  = rsqrtf(var + 1e-12f);
  float* orow = out + (size_t)row * H_;
#pragma unroll
  for (int j = 0; j < 3; ++j) {
    int c = tid + j * 256;
    orow[c] = (v[j] - mean) * inv * gamma[c] + beta[c];
  }
}

// ---------------------------------------------------------------------------
extern "C" void kernel_launch(void* const* d_in, const int* in_sizes, int n_in,
                              void* d_out, int out_size, void* d_ws,
                              size_t ws_size, hipStream_t stream) {
  const float* x     = (const float*)d_in[0];  // [N, H]
  const float* w1    = (const float*)d_in[1];  // [E, H, I]
  const float* b1    = (const float*)d_in[2];  // [E, I]
  const float* w2    = (const float*)d_in[3];  // [E, I, H]
  const float* b2    = (const float*)d_in[4];  // [E, H]
  const float* gamma = (const float*)d_in[5];  // [H]
  const float* beta  = (const float*)d_in[6];  // [H]
  float* out = (float*)d_out;

  // Workspace layout (192 MiB):
  //   w1t  [E][I][H] bf16 @ 0           (37,748,736 B)
  //   w2t  [E][H][I] bf16 @ 37748736    (37,748,736 B)
  //   x_bf [N][H]    bf16 @ 75497472    (25,165,824 B; aliased by yraw)
  //   inter[E][T][I] bf16 @ 100663296   (100,663,296 B)
  char* ws = (char*)d_ws;
  __hip_bfloat16* w1t   = (__hip_bfloat16*)(ws);
  __hip_bfloat16* w2t   = (__hip_bfloat16*)(ws + 37748736);
  __hip_bfloat16* x_bf  = (__hip_bfloat16*)(ws + 75497472);
  __hip_bfloat16* inter = (__hip_bfloat16*)(ws + 100663296);
  __hip_bfloat16* yraw  = x_bf;  // x_bf dead after GEMM1; safe alias

  cvt_bf16_kernel<<<(NTOK * H_) / (256 * 4), 256, 0, stream>>>(x, x_bf);
  transpose_cvt_kernel<<<dim3(I_ / 64, H_ / 64, E_), 256, 0, stream>>>(
      w1, w1t, H_, I_);
  transpose_cvt_kernel<<<dim3(H_ / 64, I_ / 64, E_), 256, 0, stream>>>(
      w2, w2t, I_, H_);
  // GEMM1 + bias + GELU -> inter : 8*12*8 = 768 blocks (3 full CU rounds)
  gemm8p_kernel<H_, I_, true>
      <<<E_ * (T_ / 256) * (I_ / 256), 512, 0, stream>>>(x_bf, w1t, b1, inter);
  // GEMM2 + bias -> yraw : 8*3*8 = 192 blocks
  gemm8p_kernel<I_, H_, false>
      <<<E_ * (T_ / 256) * (H_ / 256), 512, 0, stream>>>(inter, w2t, b2, yraw);
  ln_kernel<<<NTOK, 256, 0, stream>>>(yraw, x, gamma, beta, out);
}

// Round 4
// 253.008 us; speedup vs baseline: 1.6012x; 1.0583x over previous
//
#include <hip/hip_runtime.h>
#include <hip/hip_bf16.h>
#include <math.h>

// Problem dims (fixed by setup_inputs)
#define E_   8
#define H_   768
#define I_   3072
#define T_   2048
#define NTOK (E_ * T_)

typedef __attribute__((ext_vector_type(8))) short bf16x8;   // 8 bf16 = 4 VGPRs
typedef __attribute__((ext_vector_type(4))) float f32x4;    // MFMA accum

typedef __attribute__((address_space(3))) void lds_void;
typedef const __attribute__((address_space(1))) void gl_void;

__device__ __forceinline__ void gload16(const void* g, void* l) {
  // 16B async global->LDS. LDS dest is wave-uniform base + lane*16.
  __builtin_amdgcn_global_load_lds((gl_void*)g, (lds_void*)l, 16, 0, 0);
}

// Compiler-only fence (0 instructions) + raw HW barrier. NOT __syncthreads():
// that would emit s_waitcnt vmcnt(0) and drain the prefetch pipeline (T4).
#define FENCE() asm volatile("" ::: "memory")
#define BAR()                         \
  do {                                \
    FENCE();                          \
    __builtin_amdgcn_s_barrier();     \
    FENCE();                          \
  } while (0)
#define VMWAIT(n) asm volatile("s_waitcnt vmcnt(" #n ")" ::: "memory")

#define MFMA16(a, b, c) __builtin_amdgcn_mfma_f32_16x16x32_bf16(a, b, c, 0, 0, 0)

// Fast GELU: v * sigmoid(1.5957691*(v + 0.044715 v^3)); |err| ~3e-4 << bf16
// storage error of the intermediate. (Round-2 verified, absmax 0.031.)
__device__ __forceinline__ float gelu_fast(float v) {
  float inner = v * fmaf(v * v, 0.044715f, 1.0f);
  float e = __builtin_amdgcn_exp2f(inner * -2.3022082f);
  return v * __builtin_amdgcn_rcpf(1.0f + e);
}

// ---------------------------------------------------------------------------
// fp32 -> bf16 elementwise convert
// ---------------------------------------------------------------------------
__global__ __launch_bounds__(256) void cvt_bf16_kernel(
    const float* __restrict__ in, __hip_bfloat16* __restrict__ out) {
  int i = (blockIdx.x * 256 + threadIdx.x) * 4;
  float4 v = *(const float4*)(in + i);
  __align__(8) __hip_bfloat16 t[4];
  t[0] = __float2bfloat16(v.x);
  t[1] = __float2bfloat16(v.y);
  t[2] = __float2bfloat16(v.z);
  t[3] = __float2bfloat16(v.w);
  *(ushort4*)(out + i) = *(const ushort4*)t;
}

// ---------------------------------------------------------------------------
// [E][R][C] fp32 -> [E][C][R] bf16 (64x64 LDS tiles)
// ---------------------------------------------------------------------------
__global__ __launch_bounds__(256) void transpose_cvt_kernel(
    const float* __restrict__ src, __hip_bfloat16* __restrict__ dst,
    int R, int C) {
  __shared__ __hip_bfloat16 tile[64][65];
  int e  = blockIdx.z;
  int c0 = blockIdx.x * 64;
  int r0 = blockIdx.y * 64;
  const float* s = src + (size_t)e * R * C;
  __hip_bfloat16* d = dst + (size_t)e * R * C;
  int tx = threadIdx.x & 63, ty = threadIdx.x >> 6;
#pragma unroll
  for (int r = ty; r < 64; r += 4)
    tile[r][tx] = __float2bfloat16(s[(size_t)(r0 + r) * C + c0 + tx]);
  __syncthreads();
#pragma unroll
  for (int r = ty; r < 64; r += 4)
    d[(size_t)(c0 + r) * R + r0 + tx] = tile[tx][r];
}

// ---------------------------------------------------------------------------
// Grouped GEMM, 256x256 8-phase template (T1+T2+T3+T4+T5), BK=64, 512 thr
// = 8 waves (2M x 4N), per-wave 128x64 out, mfma_f32_16x16x32_bf16.
//
// LDS: sA/sB[2 buf][2 half][128][64] bf16 = 128 KiB total.
//   A-half h = tile rows {r : (r>>6)&1 == h}; B-half h = cols {n:(n>>5)&1==h}.
// Phase quadrants (mh,nh): P0=(0,0) P1=(0,1) P2=(1,1) P3=(1,0); each phase
// first-needs exactly one new half: A0+B0@P0, B1@P1, A1@P2, none@P3.
//
// DERIVED-WAITS schedule (round-4 fix): waits sit in the CONSUMER phase,
// immediately before that half's ds_reads, counted by FIFO vmcnt (m135).
// Stage order per tile kt (targets buf p^1, data kt+1): P0:A0' P1:B0'
// P2:B1' P3:A1'. Steady-state invariant entering P0: outstanding =
// [A0,B0,B1,A1] of tile kt = 8 loads, all issued during kt-1 -> every load
// has 3-4 phases of slack (vs 1 phase in the round-3 schedule).
//   P0: vmcnt(4) lands A0,B0   (8 -> 4; then stage A0' -> 6)
//   P1: vmcnt(4) lands B1      (6 -> 4; stage B0' -> 6)
//   P2: vmcnt(4) lands A1      (6 -> 4; stage B1' -> 6)
//   P3: no wait                (stage A1' -> 8)  [invariant restored]
// BAR comes AFTER the wait (vmcnt is per-wave; ds_reads consume other
// waves' staged rows). One barrier per phase P0-P2; none at P3 (the last
// LDS read of a buffer is >=2 barriers upstream of its next DMA write).
// Last tile peeled with waits 4/2/0 and no stages. Never vmcnt(0) mid-loop.
//
// T2 swizzle: LDS linear (gload_lds), global source col-group pre-swizzled
// cg = c8 ^ (lr&7); reads XOR the same. Bank conflicts measured 0 (round 3).
// ---------------------------------------------------------------------------
template <int K, int N, bool GELU>
__global__ __launch_bounds__(512, 2) void gemm8p_kernel(
    const __hip_bfloat16* __restrict__ A,
    const __hip_bfloat16* __restrict__ B,
    const float* __restrict__ bias,
    __hip_bfloat16* __restrict__ out) {
  constexpr int MT = T_ / 256;
  constexpr int NT = N / 256;
  constexpr int KT = K / 64;

  __shared__ __hip_bfloat16 sA[2][2][128][64];
  __shared__ __hip_bfloat16 sB[2][2][128][64];

  // T1: bijective XCD swizzle (gridDim.x % 8 == 0 for both GEMMs).
  int nwg = gridDim.x;
  int b0  = blockIdx.x;
  int bid = (b0 & 7) * (nwg >> 3) + (b0 >> 3);

  int e   = bid / (MT * NT);
  int rr_ = bid % (MT * NT);
  int bm  = rr_ / NT;
  int bn  = rr_ % NT;

  const __hip_bfloat16* Ae = A + (size_t)e * T_ * K + (size_t)bm * 256 * K;
  const __hip_bfloat16* Be = B + (size_t)e * N  * K + (size_t)bn * 256 * K;

  int tid  = threadIdx.x;
  int lane = tid & 63;
  int wid  = tid >> 6;
  int wr   = wid >> 2;   // 0..1 (M)
  int wc   = wid & 3;    // 0..3 (N)
  int l15  = lane & 15;
  int l16h = lane >> 4;  // 0..3

  // --- staging geometry: idx = l*512 + tid, lr = idx>>3, c8 = idx&7
  int i0 = tid, i1 = 512 + tid;
  int lr0 = i0 >> 3, c80 = i0 & 7, cg0 = c80 ^ (lr0 & 7);
  int lr1 = i1 >> 3, c81 = i1 & 7, cg1 = c81 ^ (lr1 & 7);
  int rA0 = ((lr0 >> 6) << 7) | (lr0 & 63);  // + h<<6
  int rA1 = ((lr1 >> 6) << 7) | (lr1 & 63);
  int rB0 = ((lr0 >> 5) << 6) | (lr0 & 31);  // + h<<5
  int rB1 = ((lr1 >> 5) << 6) | (lr1 & 31);

  auto stageA = [&](int buf, int h, int kt) {
    const __hip_bfloat16* g = Ae + (size_t)kt * 64;
    gload16(g + (size_t)(rA0 | (h << 6)) * K + cg0 * 8, &sA[buf][h][lr0][c80 * 8]);
    gload16(g + (size_t)(rA1 | (h << 6)) * K + cg1 * 8, &sA[buf][h][lr1][c81 * 8]);
  };
  auto stageB = [&](int buf, int h, int kt) {
    const __hip_bfloat16* g = Be + (size_t)kt * 64;
    gload16(g + (size_t)(rB0 | (h << 5)) * K + cg0 * 8, &sB[buf][h][lr0][c80 * 8]);
    gload16(g + (size_t)(rB1 | (h << 5)) * K + cg1 * 8, &sB[buf][h][lr1][c81 * 8]);
  };

  // --- fragment-read geometry (T2 read-side XOR)
  int laBase = wr * 64 + l15;  // + mf*16, within A-half
  int lbBase = wc * 32 + l15;  // + (nf&1)*16, within B-half
  int s7   = l15 & 7;
  int cgr0 = ((0 | l16h) ^ s7) * 8;  // ks=0 element offset
  int cgr1 = ((4 | l16h) ^ s7) * 8;  // ks=1

  f32x4 acc[8][4] = {};  // [mh*4+mf][nf]
  bf16x8 af[4][2], bfv[4][2];

  // ---- prologue: stage all 4 halves of tile 0 in FIFO order A0 B0 B1 A1.
  // Entering the loop, outstanding = 8 = the steady-state P0 invariant.
  stageA(0, 0, 0);
  stageB(0, 0, 0);
  stageB(0, 1, 0);
  stageA(0, 1, 0);

  auto ktile = [&](int kt, int p, bool pf) {
    // ---- P0: quadrant (0,0). Needs A0,B0.
    VMWAIT(4);  // lands A0,B0 (oldest 4 of 8)
    BAR();
#pragma unroll
    for (int mf = 0; mf < 4; ++mf) {
      int la = laBase + mf * 16;
      af[mf][0] = *(const bf16x8*)&sA[p][0][la][cgr0];
      af[mf][1] = *(const bf16x8*)&sA[p][0][la][cgr1];
    }
#pragma unroll
    for (int nf = 0; nf < 2; ++nf) {
      int lb = lbBase + nf * 16;
      bfv[nf][0] = *(const bf16x8*)&sB[p][0][lb][cgr0];
      bfv[nf][1] = *(const bf16x8*)&sB[p][0][lb][cgr1];
    }
    if (pf) stageA(p ^ 1, 0, kt + 1);
    __builtin_amdgcn_s_setprio(1);
#pragma unroll
    for (int mf = 0; mf < 4; ++mf)
#pragma unroll
      for (int nf = 0; nf < 2; ++nf) {
        acc[mf][nf] = MFMA16(af[mf][0], bfv[nf][0], acc[mf][nf]);
        acc[mf][nf] = MFMA16(af[mf][1], bfv[nf][1], acc[mf][nf]);
      }
    __builtin_amdgcn_s_setprio(0);
    // ---- P1: quadrant (0,1). Needs B1.
    if (pf) { VMWAIT(4); } else { VMWAIT(2); }  // lands B1
    BAR();
#pragma unroll
    for (int nf = 0; nf < 2; ++nf) {
      int lb = lbBase + nf * 16;
      bfv[2 + nf][0] = *(const bf16x8*)&sB[p][1][lb][cgr0];
      bfv[2 + nf][1] = *(const bf16x8*)&sB[p][1][lb][cgr1];
    }
    if (pf) stageB(p ^ 1, 0, kt + 1);
    __builtin_amdgcn_s_setprio(1);
#pragma unroll
    for (int mf = 0; mf < 4; ++mf)
#pragma unroll
      for (int nf = 2; nf < 4; ++nf) {
        acc[mf][nf] = MFMA16(af[mf][0], bfv[nf][0], acc[mf][nf]);
        acc[mf][nf] = MFMA16(af[mf][1], bfv[nf][1], acc[mf][nf]);
      }
    __builtin_amdgcn_s_setprio(0);
    // ---- P2: quadrant (1,1). Needs A1 (af overwrite).
    if (pf) { VMWAIT(4); } else { VMWAIT(0); }  // lands A1
    BAR();
#pragma unroll
    for (int mf = 0; mf < 4; ++mf) {
      int la = laBase + mf * 16;
      af[mf][0] = *(const bf16x8*)&sA[p][1][la][cgr0];
      af[mf][1] = *(const bf16x8*)&sA[p][1][la][cgr1];
    }
    if (pf) stageB(p ^ 1, 1, kt + 1);
    __builtin_amdgcn_s_setprio(1);
#pragma unroll
    for (int mf = 0; mf < 4; ++mf)
#pragma unroll
      for (int nf = 2; nf < 4; ++nf) {
        acc[4 + mf][nf] = MFMA16(af[mf][0], bfv[nf][0], acc[4 + mf][nf]);
        acc[4 + mf][nf] = MFMA16(af[mf][1], bfv[nf][1], acc[4 + mf][nf]);
      }
    __builtin_amdgcn_s_setprio(0);
    // ---- P3: quadrant (1,0). No new LDS data, no wait, no barrier.
    if (pf) stageA(p ^ 1, 1, kt + 1);
    __builtin_amdgcn_s_setprio(1);
#pragma unroll
    for (int mf = 0; mf < 4; ++mf)
#pragma unroll
      for (int nf = 0; nf < 2; ++nf) {
        acc[4 + mf][nf] = MFMA16(af[mf][0], bfv[nf][0], acc[4 + mf][nf]);
        acc[4 + mf][nf] = MFMA16(af[mf][1], bfv[nf][1], acc[4 + mf][nf]);
      }
    __builtin_amdgcn_s_setprio(0);
  };

  int p = 0;
  for (int kt = 0; kt < KT - 1; ++kt) {
    ktile(kt, p, true);
    p ^= 1;
  }
  ktile(KT - 1, p, false);  // peeled: no prefetch; waits 4/2/0

  // ---- epilogue: +bias, optional GELU, bf16 store.
  // C/D mapping (m89): col = lane&15, row = (lane>>4)*4 + r.
  const float* be = bias + (size_t)e * N + bn * 256;
  __hip_bfloat16* oe =
      out + (size_t)e * T_ * N + (size_t)(bm * 256) * N + bn * 256;
  int r4 = l16h * 4;
#pragma unroll
  for (int mi = 0; mi < 8; ++mi) {
    int mh = mi >> 2, mf = mi & 3;
    int rowb = wr * 128 + mh * 64 + mf * 16 + r4;
#pragma unroll
    for (int nf = 0; nf < 4; ++nf) {
      int cc   = wc * 64 + nf * 16 + l15;
      float bv = be[cc];
#pragma unroll
      for (int r = 0; r < 4; ++r) {
        float v = acc[mi][nf][r] + bv;
        if (GELU) v = gelu_fast(v);
        oe[(size_t)(rowb + r) * N + cc] = __float2bfloat16(v);
      }
    }
  }
}

// ---------------------------------------------------------------------------
// Residual + LayerNorm: one 256-thread block per token row (H=768 = 3*256).
// ---------------------------------------------------------------------------
__global__ __launch_bounds__(256) void ln_kernel(
    const __hip_bfloat16* __restrict__ yraw, const float* __restrict__ x,
    const float* __restrict__ gamma, const float* __restrict__ beta,
    float* __restrict__ out) {
  int row  = blockIdx.x;
  int tid  = threadIdx.x;
  int lane = tid & 63, wid = tid >> 6;
  const __hip_bfloat16* yr = yraw + (size_t)row * H_;
  const float* xr = x + (size_t)row * H_;

  float v[3];
  float s = 0.f, s2 = 0.f;
#pragma unroll
  for (int j = 0; j < 3; ++j) {
    int c   = tid + j * 256;
    float t = __bfloat162float(yr[c]) + xr[c];
    v[j] = t;
    s += t;
    s2 += t * t;
  }
#pragma unroll
  for (int o = 32; o > 0; o >>= 1) {
    s  += __shfl_down(s, o);
    s2 += __shfl_down(s2, o);
  }
  __shared__ float ls[4], ls2[4];
  if (lane == 0) { ls[wid] = s; ls2[wid] = s2; }
  __syncthreads();
  float tot  = ls[0] + ls[1] + ls[2] + ls[3];
  float tot2 = ls2[0] + ls2[1] + ls2[2] + ls2[3];
  float mean = tot * (1.0f / 768.0f);
  float var  = tot2 * (1.0f / 768.0f) - mean * mean;
  float inv  = rsqrtf(var + 1e-12f);
  float* orow = out + (size_t)row * H_;
#pragma unroll
  for (int j = 0; j < 3; ++j) {
    int c = tid + j * 256;
    orow[c] = (v[j] - mean) * inv * gamma[c] + beta[c];
  }
}

// ---------------------------------------------------------------------------
extern "C" void kernel_launch(void* const* d_in, const int* in_sizes, int n_in,
                              void* d_out, int out_size, void* d_ws,
                              size_t ws_size, hipStream_t stream) {
  const float* x     = (const float*)d_in[0];  // [N, H]
  const float* w1    = (const float*)d_in[1];  // [E, H, I]
  const float* b1    = (const float*)d_in[2];  // [E, I]
  const float* w2    = (const float*)d_in[3];  // [E, I, H]
  const float* b2    = (const float*)d_in[4];  // [E, H]
  const float* gamma = (const float*)d_in[5];  // [H]
  const float* beta  = (const float*)d_in[6];  // [H]
  float* out = (float*)d_out;

  // Workspace layout (192 MiB):
  //   w1t  [E][I][H] bf16 @ 0           (37,748,736 B)
  //   w2t  [E][H][I] bf16 @ 37748736    (37,748,736 B)
  //   x_bf [N][H]    bf16 @ 75497472    (25,165,824 B; aliased by yraw)
  //   inter[E][T][I] bf16 @ 100663296   (100,663,296 B)
  char* ws = (char*)d_ws;
  __hip_bfloat16* w1t   = (__hip_bfloat16*)(ws);
  __hip_bfloat16* w2t   = (__hip_bfloat16*)(ws + 37748736);
  __hip_bfloat16* x_bf  = (__hip_bfloat16*)(ws + 75497472);
  __hip_bfloat16* inter = (__hip_bfloat16*)(ws + 100663296);
  __hip_bfloat16* yraw  = x_bf;  // x_bf dead after GEMM1; safe alias

  cvt_bf16_kernel<<<(NTOK * H_) / (256 * 4), 256, 0, stream>>>(x, x_bf);
  transpose_cvt_kernel<<<dim3(I_ / 64, H_ / 64, E_), 256, 0, stream>>>(
      w1, w1t, H_, I_);
  transpose_cvt_kernel<<<dim3(H_ / 64, I_ / 64, E_), 256, 0, stream>>>(
      w2, w2t, I_, H_);
  // GEMM1 + bias + GELU -> inter : 768 blocks (3 full CU rounds)
  gemm8p_kernel<H_, I_, true>
      <<<E_ * (T_ / 256) * (I_ / 256), 512, 0, stream>>>(x_bf, w1t, b1, inter);
  // GEMM2 + bias -> yraw : 192 blocks
  gemm8p_kernel<I_, H_, false>
      <<<E_ * (T_ / 256) * (H_ / 256), 512, 0, stream>>>(inter, w2t, b2, yraw);
  ln_kernel<<<NTOK, 256, 0, stream>>>(yraw, x, gamma, beta, out);
}

// Round 5
// 252.771 us; speedup vs baseline: 1.6027x; 1.0009x over previous
//
#include <hip/hip_runtime.h>
#include <hip/hip_bf16.h>
#include <math.h>

// Problem dims (fixed by setup_inputs)
#define E_   8
#define H_   768
#define I_   3072
#define T_   2048
#define NTOK (E_ * T_)

typedef __attribute__((ext_vector_type(8))) short bf16x8;   // 8 bf16 = 4 VGPRs
typedef __attribute__((ext_vector_type(4))) float f32x4;    // MFMA accum

typedef __attribute__((address_space(3))) void lds_void;
typedef const __attribute__((address_space(1))) void gl_void;

__device__ __forceinline__ void gload16(const void* g, void* l) {
  // 16B async global->LDS. LDS dest is wave-uniform base + lane*16.
  __builtin_amdgcn_global_load_lds((gl_void*)g, (lds_void*)l, 16, 0, 0);
}

// Compiler-only fence (0 instructions) + raw HW barrier. NOT __syncthreads():
// that would emit s_waitcnt vmcnt(0) and drain the prefetch pipeline (T4).
#define FENCE() asm volatile("" ::: "memory")
#define BAR()                         \
  do {                                \
    FENCE();                          \
    __builtin_amdgcn_s_barrier();     \
    FENCE();                          \
  } while (0)
#define VMWAIT(n) asm volatile("s_waitcnt vmcnt(" #n ")" ::: "memory")

#define MFMA16(a, b, c) __builtin_amdgcn_mfma_f32_16x16x32_bf16(a, b, c, 0, 0, 0)

// Fast GELU: v * sigmoid(1.5957691*(v + 0.044715 v^3)); |err| ~3e-4 << bf16
// storage error of the intermediate. (Round-2 verified, absmax 0.031.)
__device__ __forceinline__ float gelu_fast(float v) {
  float inner = v * fmaf(v * v, 0.044715f, 1.0f);
  float e = __builtin_amdgcn_exp2f(inner * -2.3022082f);
  return v * __builtin_amdgcn_rcpf(1.0f + e);
}

// ---------------------------------------------------------------------------
// fp32 -> bf16 elementwise convert
// ---------------------------------------------------------------------------
__global__ __launch_bounds__(256) void cvt_bf16_kernel(
    const float* __restrict__ in, __hip_bfloat16* __restrict__ out) {
  int i = (blockIdx.x * 256 + threadIdx.x) * 4;
  float4 v = *(const float4*)(in + i);
  __align__(8) __hip_bfloat16 t[4];
  t[0] = __float2bfloat16(v.x);
  t[1] = __float2bfloat16(v.y);
  t[2] = __float2bfloat16(v.z);
  t[3] = __float2bfloat16(v.w);
  *(ushort4*)(out + i) = *(const ushort4*)t;
}

// ---------------------------------------------------------------------------
// [E][R][C] fp32 -> [E][C][R] bf16 (64x64 LDS tiles)
// ---------------------------------------------------------------------------
__global__ __launch_bounds__(256) void transpose_cvt_kernel(
    const float* __restrict__ src, __hip_bfloat16* __restrict__ dst,
    int R, int C) {
  __shared__ __hip_bfloat16 tile[64][65];
  int e  = blockIdx.z;
  int c0 = blockIdx.x * 64;
  int r0 = blockIdx.y * 64;
  const float* s = src + (size_t)e * R * C;
  __hip_bfloat16* d = dst + (size_t)e * R * C;
  int tx = threadIdx.x & 63, ty = threadIdx.x >> 6;
#pragma unroll
  for (int r = ty; r < 64; r += 4)
    tile[r][tx] = __float2bfloat16(s[(size_t)(r0 + r) * C + c0 + tx]);
  __syncthreads();
#pragma unroll
  for (int r = ty; r < 64; r += 4)
    d[(size_t)(c0 + r) * R + r0 + tx] = tile[tx][r];
}

// ---------------------------------------------------------------------------
// Grouped GEMM, 256xBN 2-phase merged schedule (round-5), BK=64, 512 thr =
// 8 waves (2M x 4N); per-wave 128 x BN/4 out, mfma_f32_16x16x32_bf16.
//
// Round-4 post-mortem: 4 barrier-aligned phases alternate {LDS-read window}
// / {MFMA window} across all 8 waves -> ~34% MfmaUtil ceiling. Fix: merge to
// 2 phases/K-tile so each phase = one basic block {reads + stage + 32 MFMA};
// the compiler's fine-grained lgkmcnt lets MFMAs start as soon as their
// fragments land, hiding the LDS-read time (reads ~770 cyc < MFMA ~1240 cyc
// per phase per CU). Barriers: 2/tile (was 3).
//
// LDS: sA[2 buf][2 half][128][64], sB[2 buf][BN][64] bf16.
//   A-half h = tile rows {r : (r>>6)&1 == h}  (so wave wr's mh=h rows live
//   in half h at local row wr*64 + mf*16 + l15). B staged whole.
// Ph0 consumes A-half0 + all B (MFMA quadrants (0,*)); Ph1 consumes A-half1.
//
// Stage order per tile kt (targets buf p^1, data kt+1), FIFO instr units:
//   Ph0: A0' (2) + B' (BN/64)   Ph1: A1' (2)
// Waits (consumer side, counted; never 0 mid-loop):
//   Ph0 entry: outstanding = [A0,B,A1](kt) = 4+BN/64; VMWAIT(2) lands A0,B
//              (slack = 1 full tile ~ 2 phases).
//   Ph1 entry: outstanding = 2 + (2+BN/64); VMWAIT(4+BN/64) lands A1.
//   Peeled last tile: VMWAIT(2) / VMWAIT(0).
// WAR safety: buf p^1's last reads (Ph1 of kt-1) complete before that wave's
// MFMAs, hence before Ph0(kt)'s barrier; DMA into p^1 issues after it.
//
// T2 swizzle: LDS linear (gload_lds), global source col-group pre-swizzled
// cg = c8 ^ (lr&7); reads XOR the same. Bank conflicts measured 0 (round 3).
// T1 XCD swizzle: both grids are multiples of 8.
// ---------------------------------------------------------------------------
template <int K, int N, int BN, bool GELU>
__global__ __launch_bounds__(512, 2) void gemm2p_kernel(
    const __hip_bfloat16* __restrict__ A,
    const __hip_bfloat16* __restrict__ B,
    const float* __restrict__ bias,
    __hip_bfloat16* __restrict__ out) {
  constexpr int MT = T_ / 256;
  constexpr int NT = N / BN;
  constexpr int KT = K / 64;
  constexpr int NF = BN / 64;   // B frags per wave (4 or 3)
  constexpr int WCW = BN / 4;   // per-wave col width (64 or 48)
  constexpr int BPASS = BN / 64;  // B stage passes (4 or 3)

  __shared__ __hip_bfloat16 sA[2][2][128][64];
  __shared__ __hip_bfloat16 sB[2][BN][64];

  // T1: bijective XCD swizzle (gridDim.x % 8 == 0 for both GEMMs).
  int nwg = gridDim.x;
  int b0  = blockIdx.x;
  int bid = (b0 & 7) * (nwg >> 3) + (b0 >> 3);

  int e   = bid / (MT * NT);
  int rr_ = bid % (MT * NT);
  int bm  = rr_ / NT;
  int bn  = rr_ % NT;

  const __hip_bfloat16* Ae = A + (size_t)e * T_ * K + (size_t)bm * 256 * K;
  const __hip_bfloat16* Be = B + (size_t)e * N  * K + (size_t)bn * BN * K;

  int tid  = threadIdx.x;
  int lane = tid & 63;
  int wid  = tid >> 6;
  int wr   = wid >> 2;   // 0..1 (M)
  int wc   = wid & 3;    // 0..3 (N)
  int l15  = lane & 15;
  int l16h = lane >> 4;  // 0..3

  // --- staging geometry (A halves: 2 passes each; idx = pass*512 + tid)
  int i0 = tid, i1 = 512 + tid;
  int lr0 = i0 >> 3, c80 = i0 & 7, cg0 = c80 ^ (lr0 & 7);
  int lr1 = i1 >> 3, c81 = i1 & 7, cg1 = c81 ^ (lr1 & 7);
  int rA0 = ((lr0 >> 6) << 7) | (lr0 & 63);  // + h<<6
  int rA1 = ((lr1 >> 6) << 7) | (lr1 & 63);

  auto stageA = [&](int buf, int h, int kt) {
    const __hip_bfloat16* g = Ae + (size_t)kt * 64;
    gload16(g + (size_t)(rA0 | (h << 6)) * K + cg0 * 8, &sA[buf][h][lr0][c80 * 8]);
    gload16(g + (size_t)(rA1 | (h << 6)) * K + cg1 * 8, &sA[buf][h][lr1][c81 * 8]);
  };
  auto stageB = [&](int buf, int kt) {
    const __hip_bfloat16* g = Be + (size_t)kt * 64;
#pragma unroll
    for (int q = 0; q < BPASS; ++q) {
      int idx = q * 512 + tid;
      int lr = idx >> 3, c8 = idx & 7;
      int cg = c8 ^ (lr & 7);
      gload16(g + (size_t)lr * K + cg * 8, &sB[buf][lr][c8 * 8]);
    }
  };

  // --- fragment-read geometry (T2 read-side XOR)
  int laBase = wr * 64 + l15;   // + mf*16, within A-half
  int lbBase = wc * WCW + l15;  // + nf*16  (WCW,16 are multiples of 8 -> &7 = s7)
  int s7   = l15 & 7;
  int cgr0 = ((0 | l16h) ^ s7) * 8;  // ks=0 element offset
  int cgr1 = ((4 | l16h) ^ s7) * 8;  // ks=1

  f32x4 acc[8][NF] = {};  // [mh*4+mf][nf]
  bf16x8 af[4][2], bfv[NF][2];

  // ---- prologue: stage tile 0 in FIFO order A0, B, A1.
  stageA(0, 0, 0);
  stageB(0, 0);
  stageA(0, 1, 0);

  auto ktile = [&](int kt, int p, bool pf) {
    // ======== Ph0: quadrants (0,*). Needs A0 + all B. ========
    VMWAIT(2);  // lands A0,B of kt (leaves A1's 2)
    BAR();
#pragma unroll
    for (int mf = 0; mf < 4; ++mf) {
      int la = laBase + mf * 16;
      af[mf][0] = *(const bf16x8*)&sA[p][0][la][cgr0];
      af[mf][1] = *(const bf16x8*)&sA[p][0][la][cgr1];
    }
#pragma unroll
    for (int nf = 0; nf < NF; ++nf) {
      int lb = lbBase + nf * 16;
      bfv[nf][0] = *(const bf16x8*)&sB[p][lb][cgr0];
      bfv[nf][1] = *(const bf16x8*)&sB[p][lb][cgr1];
    }
    if (pf) {
      stageA(p ^ 1, 0, kt + 1);
      stageB(p ^ 1, kt + 1);
    }
    __builtin_amdgcn_s_setprio(1);
#pragma unroll
    for (int mf = 0; mf < 4; ++mf)
#pragma unroll
      for (int nf = 0; nf < NF; ++nf) {
        acc[mf][nf] = MFMA16(af[mf][0], bfv[nf][0], acc[mf][nf]);
        acc[mf][nf] = MFMA16(af[mf][1], bfv[nf][1], acc[mf][nf]);
      }
    __builtin_amdgcn_s_setprio(0);
    // ======== Ph1: quadrants (1,*). Needs A1 (af overwrite). ========
    if (pf) {
      if constexpr (BN == 256) { VMWAIT(6); } else { VMWAIT(5); }  // lands A1
    } else {
      VMWAIT(0);
    }
    BAR();
#pragma unroll
    for (int mf = 0; mf < 4; ++mf) {
      int la = laBase + mf * 16;
      af[mf][0] = *(const bf16x8*)&sA[p][1][la][cgr0];
      af[mf][1] = *(const bf16x8*)&sA[p][1][la][cgr1];
    }
    if (pf) stageA(p ^ 1, 1, kt + 1);
    __builtin_amdgcn_s_setprio(1);
#pragma unroll
    for (int mf = 0; mf < 4; ++mf)
#pragma unroll
      for (int nf = 0; nf < NF; ++nf) {
        acc[4 + mf][nf] = MFMA16(af[mf][0], bfv[nf][0], acc[4 + mf][nf]);
        acc[4 + mf][nf] = MFMA16(af[mf][1], bfv[nf][1], acc[4 + mf][nf]);
      }
    __builtin_amdgcn_s_setprio(0);
  };

  int p = 0;
  for (int kt = 0; kt < KT - 1; ++kt) {
    ktile(kt, p, true);
    p ^= 1;
  }
  ktile(KT - 1, p, false);  // peeled: no prefetch; waits 2/0

  // ---- epilogue: +bias, optional GELU, bf16 store.
  // C/D mapping (m89): col = lane&15, row = (lane>>4)*4 + r.
  const float* be = bias + (size_t)e * N + bn * BN;
  __hip_bfloat16* oe =
      out + (size_t)e * T_ * N + (size_t)(bm * 256) * N + bn * BN;
  int r4 = l16h * 4;
#pragma unroll
  for (int mi = 0; mi < 8; ++mi) {
    int mh = mi >> 2, mf = mi & 3;
    int rowb = wr * 128 + mh * 64 + mf * 16 + r4;
#pragma unroll
    for (int nf = 0; nf < NF; ++nf) {
      int cc   = wc * WCW + nf * 16 + l15;
      float bv = be[cc];
#pragma unroll
      for (int r = 0; r < 4; ++r) {
        float v = acc[mi][nf][r] + bv;
        if (GELU) v = gelu_fast(v);
        oe[(size_t)(rowb + r) * N + cc] = __float2bfloat16(v);
      }
    }
  }
}

// ---------------------------------------------------------------------------
// Residual + LayerNorm: one 256-thread block per token row (H=768 = 3*256).
// ---------------------------------------------------------------------------
__global__ __launch_bounds__(256) void ln_kernel(
    const __hip_bfloat16* __restrict__ yraw, const float* __restrict__ x,
    const float* __restrict__ gamma, const float* __restrict__ beta,
    float* __restrict__ out) {
  int row  = blockIdx.x;
  int tid  = threadIdx.x;
  int lane = tid & 63, wid = tid >> 6;
  const __hip_bfloat16* yr = yraw + (size_t)row * H_;
  const float* xr = x + (size_t)row * H_;

  float v[3];
  float s = 0.f, s2 = 0.f;
#pragma unroll
  for (int j = 0; j < 3; ++j) {
    int c   = tid + j * 256;
    float t = __bfloat162float(yr[c]) + xr[c];
    v[j] = t;
    s += t;
    s2 += t * t;
  }
#pragma unroll
  for (int o = 32; o > 0; o >>= 1) {
    s  += __shfl_down(s, o);
    s2 += __shfl_down(s2, o);
  }
  __shared__ float ls[4], ls2[4];
  if (lane == 0) { ls[wid] = s; ls2[wid] = s2; }
  __syncthreads();
  float tot  = ls[0] + ls[1] + ls[2] + ls[3];
  float tot2 = ls2[0] + ls2[1] + ls2[2] + ls2[3];
  float mean = tot * (1.0f / 768.0f);
  float var  = tot2 * (1.0f / 768.0f) - mean * mean;
  float inv  = rsqrtf(var + 1e-12f);
  float* orow = out + (size_t)row * H_;
#pragma unroll
  for (int j = 0; j < 3; ++j) {
    int c = tid + j * 256;
    orow[c] = (v[j] - mean) * inv * gamma[c] + beta[c];
  }
}

// ---------------------------------------------------------------------------
extern "C" void kernel_launch(void* const* d_in, const int* in_sizes, int n_in,
                              void* d_out, int out_size, void* d_ws,
                              size_t ws_size, hipStream_t stream) {
  const float* x     = (const float*)d_in[0];  // [N, H]
  const float* w1    = (const float*)d_in[1];  // [E, H, I]
  const float* b1    = (const float*)d_in[2];  // [E, I]
  const float* w2    = (const float*)d_in[3];  // [E, I, H]
  const float* b2    = (const float*)d_in[4];  // [E, H]
  const float* gamma = (const float*)d_in[5];  // [H]
  const float* beta  = (const float*)d_in[6];  // [H]
  float* out = (float*)d_out;

  // Workspace layout (192 MiB):
  //   w1t  [E][I][H] bf16 @ 0           (37,748,736 B)
  //   w2t  [E][H][I] bf16 @ 37748736    (37,748,736 B)
  //   x_bf [N][H]    bf16 @ 75497472    (25,165,824 B; aliased by yraw)
  //   inter[E][T][I] bf16 @ 100663296   (100,663,296 B)
  char* ws = (char*)d_ws;
  __hip_bfloat16* w1t   = (__hip_bfloat16*)(ws);
  __hip_bfloat16* w2t   = (__hip_bfloat16*)(ws + 37748736);
  __hip_bfloat16* x_bf  = (__hip_bfloat16*)(ws + 75497472);
  __hip_bfloat16* inter = (__hip_bfloat16*)(ws + 100663296);
  __hip_bfloat16* yraw  = x_bf;  // x_bf dead after GEMM1; safe alias

  cvt_bf16_kernel<<<(NTOK * H_) / (256 * 4), 256, 0, stream>>>(x, x_bf);
  transpose_cvt_kernel<<<dim3(I_ / 64, H_ / 64, E_), 256, 0, stream>>>(
      w1, w1t, H_, I_);
  transpose_cvt_kernel<<<dim3(H_ / 64, I_ / 64, E_), 256, 0, stream>>>(
      w2, w2t, I_, H_);
  // GEMM1 + bias + GELU -> inter : BN=256, 8*8*12 = 768 blocks (3 CU rounds)
  gemm2p_kernel<H_, I_, 256, true>
      <<<E_ * (T_ / 256) * (I_ / 256), 512, 0, stream>>>(x_bf, w1t, b1, inter);
  // GEMM2 + bias -> yraw : BN=192, 8*8*4 = 256 blocks (exactly 1 CU round)
  gemm2p_kernel<I_, H_, 192, false>
      <<<E_ * (T_ / 256) * (H_ / 192), 512, 0, stream>>>(inter, w2t, b2, yraw);
  ln_kernel<<<NTOK, 256, 0, stream>>>(yraw, x, gamma, beta, out);
}